// Round 2
// baseline (1126.865 us; speedup 1.0000x reference)
//
#include <hip/hip_runtime.h>
#include <math.h>

// ---- problem dims ----
#define NB 2
#define NSEQ 4096
#define DMODEL 384
#define NH 8
#define DKQ 48
#define DV 48
#define TOPK 128
#define NQ (NB*NSEQ)          // 8192 total query rows

// fp32 combined projection: [q(384) | k(48) | v(48)] = 480 cols
#define QKV_COLS 480
#define C_Q 0
#define C_K 384
#define C_V 432
// fp64 indexer projection Pd[8192][128]: [qi0(32)|qi1(32)|ki(32)|w(2)|pad]
#define IDX_COLS 128
#define P_QI 0
#define P_KI 64
#define P_W  96
#define ATT_SCALE 0.14433756729740643f   // 48^-0.5

// ------------------------------------------------------------------
// Kernel 0: concatenate weights
//   Wq_cat[384][480] = [wq | wk | wv]
//   Wi_cat[384][128] = [wq_idx | wk_idx | ww_idx | 0-pad]
// ------------------------------------------------------------------
__global__ void k_concat(const float* __restrict__ wq_idx, const float* __restrict__ wk_idx,
                         const float* __restrict__ ww_idx, const float* __restrict__ wq,
                         const float* __restrict__ wk, const float* __restrict__ wv,
                         float* __restrict__ Wq_cat, float* __restrict__ Wi_cat) {
    int i = blockIdx.x * 256 + threadIdx.x;
    if (i < DMODEL * QKV_COLS) {
        int d = i / QKV_COLS, c = i % QKV_COLS;
        float v;
        if (c < 384)      v = wq[d*384 + c];
        else if (c < 432) v = wk[d*48 + (c-384)];
        else              v = wv[d*48 + (c-432)];
        Wq_cat[i] = v;
    } else {
        int j = i - DMODEL * QKV_COLS;
        if (j < DMODEL * IDX_COLS) {
            int d = j / IDX_COLS, c = j % IDX_COLS;
            float v;
            if (c < 64)       v = wq_idx[d*64 + c];
            else if (c < 96)  v = wk_idx[d*32 + (c-64)];
            else if (c < 98)  v = ww_idx[d*2 + (c-96)];
            else              v = 0.f;
            Wi_cat[j] = v;
        }
    }
}

// ------------------------------------------------------------------
// fp32 GEMM: C[M x ncols] = A[M x 384] @ W[384 x ncols]
// BM=128, BN=64, BK=16, 256 threads, 8x4 micro-tile
// ------------------------------------------------------------------
__global__ __launch_bounds__(256) void k_gemm384(const float* __restrict__ A,
                                                 const float* __restrict__ W,
                                                 float* __restrict__ C,
                                                 int ldw, int ldc, int ncols) {
    __shared__ float At[16][128];
    __shared__ float Bt[16][64];
    const int t  = threadIdx.x;
    const int tx = t & 15;
    const int ty = t >> 4;
    const int row0 = blockIdx.y * 128;
    const int col0 = blockIdx.x * 64;
    float acc[8][4] = {};

    for (int k0 = 0; k0 < DMODEL; k0 += 16) {
        for (int i = 0; i < 2; i++) {
            int lin = t + i*256;
            int m = lin >> 2, kc = lin & 3;
            float4 a = *(const float4*)(A + (size_t)(row0 + m)*DMODEL + k0 + kc*4);
            At[kc*4+0][m] = a.x; At[kc*4+1][m] = a.y;
            At[kc*4+2][m] = a.z; At[kc*4+3][m] = a.w;
        }
        {
            int kk = t >> 4, nc4 = t & 15;
            int col = col0 + nc4*4;
            float4 b;
            if (col + 3 < ncols) {
                b = *(const float4*)(W + (size_t)(k0+kk)*ldw + col);
            } else {
                float tmp[4];
                for (int j = 0; j < 4; j++)
                    tmp[j] = (col + j < ncols) ? W[(size_t)(k0+kk)*ldw + col + j] : 0.f;
                b = make_float4(tmp[0], tmp[1], tmp[2], tmp[3]);
            }
            *(float4*)&Bt[kk][nc4*4] = b;
        }
        __syncthreads();
        for (int kk = 0; kk < 16; kk++) {
            float a0[8], b0[4];
            *(float4*)&a0[0] = *(const float4*)&At[kk][ty*8];
            *(float4*)&a0[4] = *(const float4*)&At[kk][ty*8+4];
            *(float4*)&b0[0] = *(const float4*)&Bt[kk][tx*4];
            for (int i = 0; i < 8; i++)
                for (int j = 0; j < 4; j++)
                    acc[i][j] += a0[i] * b0[j];
        }
        __syncthreads();
    }
    for (int i = 0; i < 8; i++) {
        int r = row0 + ty*8 + i;
        for (int j = 0; j < 4; j++) {
            int c = col0 + tx*4 + j;
            if (c < ncols) C[(size_t)r*ldc + c] = acc[i][j];
        }
    }
}

// ------------------------------------------------------------------
// fp64-accumulated indexer projection: Pd[8192][128] = x @ Wi_cat
// BM=32, BN=128, BK=16, 256 threads, 2x8 micro-tile (double acc)
// ------------------------------------------------------------------
__global__ __launch_bounds__(256) void k_proj64(const float* __restrict__ A,
                                                const float* __restrict__ W,
                                                double* __restrict__ P) {
    __shared__ float At[16][32];
    __shared__ float Bt[16][IDX_COLS];
    const int t  = threadIdx.x;
    const int tx = t & 15;     // 16 col groups * 8 = 128
    const int ty = t >> 4;     // 16 row groups * 2 = 32
    const int row0 = blockIdx.x * 32;
    double acc[2][8] = {};

    for (int k0 = 0; k0 < DMODEL; k0 += 16) {
        if (t < 128) {
            int m = t >> 2, kc = t & 3;
            float4 a = *(const float4*)(A + (size_t)(row0 + m)*DMODEL + k0 + kc*4);
            At[kc*4+0][m] = a.x; At[kc*4+1][m] = a.y;
            At[kc*4+2][m] = a.z; At[kc*4+3][m] = a.w;
        }
        for (int i = 0; i < 2; i++) {
            int lin = t + i*256;          // 512 float4 = 16x128 floats
            int kk = lin >> 5, c4 = lin & 31;
            float4 b = *(const float4*)(W + (size_t)(k0+kk)*IDX_COLS + c4*4);
            *(float4*)&Bt[kk][c4*4] = b;
        }
        __syncthreads();
        for (int kk = 0; kk < 16; kk++) {
            float a2[2], b8[8];
            a2[0] = At[kk][ty*2]; a2[1] = At[kk][ty*2+1];
            *(float4*)&b8[0] = *(const float4*)&Bt[kk][tx*8];
            *(float4*)&b8[4] = *(const float4*)&Bt[kk][tx*8+4];
            for (int i = 0; i < 2; i++)
                for (int j = 0; j < 8; j++)
                    acc[i][j] += (double)a2[i] * (double)b8[j];
        }
        __syncthreads();
    }
    for (int i = 0; i < 2; i++)
        for (int j = 0; j < 8; j++)
            P[(size_t)(row0 + ty*2 + i)*IDX_COLS + tx*8 + j] = acc[i][j];
}

// ------------------------------------------------------------------
// fp64 index scores: S[qlocal][s] = w0*relu(qi0.ki) + w1*relu(qi1.ki)
// tile: 32 queries x 128 keys, 256 threads, 2x8 micro-tile per head
// ------------------------------------------------------------------
__global__ __launch_bounds__(256) void k_score64(const double* __restrict__ P,
                                                 double* __restrict__ S, int qstart) {
    __shared__ double qi0t[32][32];     // [d][q] 8KB
    __shared__ double qi1t[32][32];     // 8KB
    __shared__ double kit[32][128];     // [d][s] 32KB
    __shared__ double wsh[2][32];
    const int t = threadIdx.x;
    const int g0 = qstart + blockIdx.y * 32;
    const int b  = g0 / NSEQ;
    const int s0 = blockIdx.x * 128;

    for (int i = 0; i < 8; i++) {
        int lin = t + i*256;            // 2048 = 32q x 64c
        int q = lin >> 6, c = lin & 63;
        double v = P[(size_t)(g0 + q)*IDX_COLS + P_QI + c];
        if (c < 32) qi0t[c][q] = v; else qi1t[c-32][q] = v;
    }
    for (int i = 0; i < 16; i++) {
        int lin = t + i*256;            // 4096 = 128s x 32c
        int s = lin >> 5, c = lin & 31;
        kit[c][s] = P[(size_t)(b*NSEQ + s0 + s)*IDX_COLS + P_KI + c];
    }
    if (t < 64) wsh[t & 1][t >> 1] = P[(size_t)(g0 + (t >> 1))*IDX_COLS + P_W + (t & 1)];
    __syncthreads();

    const int tx = t & 15;    // key group: 8 keys
    const int ty = t >> 4;    // query group: 2 queries
    double acc0[2][8] = {}, acc1[2][8] = {};
    for (int d = 0; d < 32; d++) {
        double b8[8], a0[2], a1[2];
        for (int j = 0; j < 8; j++) b8[j] = kit[d][tx*8 + j];
        a0[0] = qi0t[d][ty*2]; a0[1] = qi0t[d][ty*2+1];
        a1[0] = qi1t[d][ty*2]; a1[1] = qi1t[d][ty*2+1];
        for (int i = 0; i < 2; i++)
            for (int j = 0; j < 8; j++) {
                acc0[i][j] += a0[i] * b8[j];
                acc1[i][j] += a1[i] * b8[j];
            }
    }
    for (int i = 0; i < 2; i++) {
        int q = ty*2 + i;
        double w0 = wsh[0][q], w1 = wsh[1][q];
        for (int j = 0; j < 8; j++) {
            double sc = w0 * fmax(acc0[i][j], 0.0) + w1 * fmax(acc1[i][j], 0.0);
            S[(size_t)(blockIdx.y*32 + q)*NSEQ + s0 + tx*8 + j] = sc;
        }
    }
}

// ------------------------------------------------------------------
// Top-128 of 4096 per query on fp64 scores: 64-bit radix select.
// Ties at the threshold taken in ascending index order (jax.lax.top_k).
// ------------------------------------------------------------------
__global__ __launch_bounds__(256) void k_topk64(const double* __restrict__ S,
                                                int* __restrict__ IDX, int qstart) {
    __shared__ unsigned long long u[NSEQ];     // 32KB
    __shared__ unsigned int hist[256];
    __shared__ unsigned int scr[256];
    __shared__ unsigned long long s_ph;
    __shared__ unsigned int s_need;
    const int t = threadIdx.x;
    const int q = blockIdx.x;
    const double* row = S + (size_t)q * NSEQ;

    for (int i = t; i < NSEQ; i += 256) {
        unsigned long long bts = (unsigned long long)__double_as_longlong(row[i]);
        u[i] = (bts & 0x8000000000000000ULL) ? ~bts : (bts | 0x8000000000000000ULL);
    }
    if (t == 0) { s_ph = 0ULL; s_need = TOPK; }
    __syncthreads();

    for (int p = 0; p < 8; p++) {
        const int sh = 56 - 8*p;
        hist[t] = 0u;
        __syncthreads();
        unsigned long long ph = s_ph;
        for (int i = t*16; i < t*16 + 16; i++) {
            unsigned long long val = u[i];
            if (p == 0 || (val >> (sh + 8)) == ph)
                atomicAdd(&hist[(unsigned int)((val >> sh) & 255ULL)], 1u);
        }
        __syncthreads();
        scr[t] = hist[t];
        __syncthreads();
        for (int d = 1; d < 256; d <<= 1) {
            unsigned int add = (t + d < 256) ? scr[t+d] : 0u;
            __syncthreads();
            scr[t] += add;
            __syncthreads();
        }
        unsigned int need = s_need;
        unsigned int sfx1 = (t < 255) ? scr[t+1] : 0u;
        if (scr[t] >= need && sfx1 < need) {
            s_ph = (ph << 8) | (unsigned long long)t;
            s_need = need - sfx1;
        }
        __syncthreads();
    }
    const unsigned long long ustar = s_ph;

    unsigned int cg = 0, ce = 0;
    for (int i = t*16; i < t*16 + 16; i++) {
        unsigned long long val = u[i];
        if (val > ustar) cg++;
        else if (val == ustar) ce++;
    }
    scr[t] = (cg << 16) | ce;
    __syncthreads();
    for (int d = 1; d < 256; d <<= 1) {
        unsigned int v = scr[t];
        if (t >= d) v += scr[t-d];
        __syncthreads();
        scr[t] = v;
        __syncthreads();
    }
    unsigned int incl = scr[t];
    unsigned int tot  = scr[255];
    unsigned int excl = incl - ((cg << 16) | ce);
    unsigned int pg = excl >> 16;
    unsigned int pe = (tot >> 16) + (excl & 0xFFFFu);
    int* orow = IDX + (size_t)(qstart + q) * TOPK;
    for (int i = t*16; i < t*16 + 16; i++) {
        unsigned long long val = u[i];
        if (val > ustar) {
            if (pg < TOPK) orow[pg] = i;
            pg++;
        } else if (val == ustar) {
            if (pe < TOPK) orow[pe] = i;
            pe++;
        }
    }
}

// ------------------------------------------------------------------
// Sparse attention: per query, 8 heads over 128 selected keys (fp32)
// ------------------------------------------------------------------
__global__ __launch_bounds__(256) void k_attn(const float* __restrict__ Y,
                                              const int* __restrict__ IDX,
                                              float* __restrict__ ctx) {
    __shared__ float Ks[TOPK][DKQ];
    __shared__ float Vs[TOPK][DV];
    __shared__ float qsh[NH*DKQ];
    __shared__ float probs[NH][TOPK];
    __shared__ int   idxs[TOPK];
    const int g = blockIdx.x;
    const int b = g / NSEQ;
    const int t = threadIdx.x;

    if (t < TOPK) idxs[t] = IDX[(size_t)g*TOPK + t];
    for (int i = t; i < NH*DKQ; i += 256) qsh[i] = Y[(size_t)g*QKV_COLS + C_Q + i];
    __syncthreads();
    for (int e = t; e < TOPK*DKQ; e += 256) {
        int j = e / DKQ, dd = e % DKQ;
        size_t roff = (size_t)(b*NSEQ + idxs[j]) * QKV_COLS;
        Ks[j][dd] = Y[roff + C_K + dd];
        Vs[j][dd] = Y[roff + C_V + dd];
    }
    __syncthreads();

    const int h  = t >> 5;
    const int j0 = t & 31;
    float lo[4];
    for (int i = 0; i < 4; i++) {
        int j = j0 + 32*i;
        float acc = 0.f;
        for (int dd = 0; dd < DKQ; dd++) acc += qsh[h*DKQ + dd] * Ks[j][dd];
        lo[i] = acc * ATT_SCALE;
    }
    float m = fmaxf(fmaxf(lo[0], lo[1]), fmaxf(lo[2], lo[3]));
    for (int d = 16; d >= 1; d >>= 1) m = fmaxf(m, __shfl_xor(m, d, 64));
    float e0[4], sum = 0.f;
    for (int i = 0; i < 4; i++) { e0[i] = __expf(lo[i] - m); sum += e0[i]; }
    for (int d = 16; d >= 1; d >>= 1) sum += __shfl_xor(sum, d, 64);
    float inv = 1.0f / sum;
    for (int i = 0; i < 4; i++) probs[h][j0 + 32*i] = e0[i] * inv;
    __syncthreads();

    for (int o = t; o < NH*DV; o += 256) {
        int hh = o / DV, dd = o % DV;
        float acc = 0.f;
        for (int j = 0; j < TOPK; j++) acc += probs[hh][j] * Vs[j][dd];
        ctx[(size_t)g*(NH*DV) + o] = acc;
    }
}

// ------------------------------------------------------------------
extern "C" void kernel_launch(void* const* d_in, const int* in_sizes, int n_in,
                              void* d_out, int out_size, void* d_ws, size_t ws_size,
                              hipStream_t stream) {
    const float* x      = (const float*)d_in[0];
    const float* wq_idx = (const float*)d_in[1];
    const float* wk_idx = (const float*)d_in[2];
    const float* ww_idx = (const float*)d_in[3];
    const float* wq     = (const float*)d_in[4];
    const float* wk     = (const float*)d_in[5];
    const float* wv     = (const float*)d_in[6];
    const float* wo     = (const float*)d_in[7];
    float* out = (float*)d_out;
    char*  ws  = (char*)d_ws;

    // byte offsets, 256B aligned
    size_t off = 0;
    auto carve = [&](size_t bytes) { size_t o = off; off = (off + bytes + 255) & ~(size_t)255; return o; };
    size_t oWq  = carve((size_t)DMODEL*QKV_COLS*4);
    size_t oWi  = carve((size_t)DMODEL*IDX_COLS*4);
    size_t oY   = carve((size_t)NQ*QKV_COLS*4);
    size_t oP   = carve((size_t)NQ*IDX_COLS*8);
    size_t oIdx = carve((size_t)NQ*TOPK*4);
    size_t oCtx = carve((size_t)NQ*NH*DV*4);
    size_t oS   = off;

    int QC = NSEQ;
    while (QC > 32 && oS + (size_t)QC*NSEQ*8 > ws_size) QC >>= 1;

    float*  Wq_cat = (float*)(ws + oWq);
    float*  Wi_cat = (float*)(ws + oWi);
    float*  Y      = (float*)(ws + oY);
    double* P      = (double*)(ws + oP);
    int*    IDX    = (int*)(ws + oIdx);
    float*  ctx    = (float*)(ws + oCtx);
    double* S      = (double*)(ws + oS);

    int ncat = DMODEL*QKV_COLS + DMODEL*IDX_COLS;
    k_concat<<<(ncat + 255)/256, 256, 0, stream>>>(wq_idx, wk_idx, ww_idx, wq, wk, wv, Wq_cat, Wi_cat);
    k_gemm384<<<dim3((QKV_COLS + 63)/64, NQ/128), 256, 0, stream>>>(x, Wq_cat, Y, QKV_COLS, QKV_COLS, QKV_COLS);
    k_proj64<<<NQ/32, 256, 0, stream>>>(x, Wi_cat, P);
    for (int qs = 0; qs < NQ; qs += QC) {
        k_score64<<<dim3(NSEQ/128, QC/32), 256, 0, stream>>>(P, S, qs);
        k_topk64<<<QC, 256, 0, stream>>>(S, IDX, qs);
    }
    k_attn<<<NQ, 256, 0, stream>>>(Y, IDX, ctx);
    k_gemm384<<<dim3(DMODEL/64, NQ/128), 256, 0, stream>>>(ctx, wo, out, DMODEL, DMODEL, DMODEL);
}

// Round 3
// 833.655 us; speedup vs baseline: 1.3517x; 1.3517x over previous
//
#include <hip/hip_runtime.h>
#include <math.h>

// ---- problem dims ----
#define NB 2
#define NSEQ 4096
#define DMODEL 384
#define NH 8
#define DKQ 48
#define DV 48
#define TOPK 128
#define NQ (NB*NSEQ)          // 8192 total query rows

// fp32 combined projection: [q(384) | k(48) | v(48)] = 480 cols
#define QKV_COLS 480
#define C_Q 0
#define C_K 384
#define C_V 432
// fp64 indexer projection Pd[8192][128]: [qi0(32)|qi1(32)|ki(32)|w(2)|pad]
#define IDX_COLS 128
#define P_QI 0
#define P_KI 64
#define P_W  96
#define ATT_SCALE 0.14433756729740643f   // 48^-0.5

// ------------------------------------------------------------------
// Kernel 0: concatenate weights
// ------------------------------------------------------------------
__global__ void k_concat(const float* __restrict__ wq_idx, const float* __restrict__ wk_idx,
                         const float* __restrict__ ww_idx, const float* __restrict__ wq,
                         const float* __restrict__ wk, const float* __restrict__ wv,
                         float* __restrict__ Wq_cat, float* __restrict__ Wi_cat) {
    int i = blockIdx.x * 256 + threadIdx.x;
    if (i < DMODEL * QKV_COLS) {
        int d = i / QKV_COLS, c = i % QKV_COLS;
        float v;
        if (c < 384)      v = wq[d*384 + c];
        else if (c < 432) v = wk[d*48 + (c-384)];
        else              v = wv[d*48 + (c-432)];
        Wq_cat[i] = v;
    } else {
        int j = i - DMODEL * QKV_COLS;
        if (j < DMODEL * IDX_COLS) {
            int d = j / IDX_COLS, c = j % IDX_COLS;
            float v;
            if (c < 64)       v = wq_idx[d*64 + c];
            else if (c < 96)  v = wk_idx[d*32 + (c-64)];
            else if (c < 98)  v = ww_idx[d*2 + (c-96)];
            else              v = 0.f;
            Wi_cat[j] = v;
        }
    }
}

// ------------------------------------------------------------------
// fp32 GEMM: C[M x ncols] = A[M x 384] @ W[384 x ncols]
// ------------------------------------------------------------------
__global__ __launch_bounds__(256) void k_gemm384(const float* __restrict__ A,
                                                 const float* __restrict__ W,
                                                 float* __restrict__ C,
                                                 int ldw, int ldc, int ncols) {
    __shared__ float At[16][128];
    __shared__ float Bt[16][64];
    const int t  = threadIdx.x;
    const int tx = t & 15;
    const int ty = t >> 4;
    const int row0 = blockIdx.y * 128;
    const int col0 = blockIdx.x * 64;
    float acc[8][4] = {};

    for (int k0 = 0; k0 < DMODEL; k0 += 16) {
        for (int i = 0; i < 2; i++) {
            int lin = t + i*256;
            int m = lin >> 2, kc = lin & 3;
            float4 a = *(const float4*)(A + (size_t)(row0 + m)*DMODEL + k0 + kc*4);
            At[kc*4+0][m] = a.x; At[kc*4+1][m] = a.y;
            At[kc*4+2][m] = a.z; At[kc*4+3][m] = a.w;
        }
        {
            int kk = t >> 4, nc4 = t & 15;
            int col = col0 + nc4*4;
            float4 b;
            if (col + 3 < ncols) {
                b = *(const float4*)(W + (size_t)(k0+kk)*ldw + col);
            } else {
                float tmp[4];
                for (int j = 0; j < 4; j++)
                    tmp[j] = (col + j < ncols) ? W[(size_t)(k0+kk)*ldw + col + j] : 0.f;
                b = make_float4(tmp[0], tmp[1], tmp[2], tmp[3]);
            }
            *(float4*)&Bt[kk][nc4*4] = b;
        }
        __syncthreads();
        for (int kk = 0; kk < 16; kk++) {
            float a0[8], b0[4];
            *(float4*)&a0[0] = *(const float4*)&At[kk][ty*8];
            *(float4*)&a0[4] = *(const float4*)&At[kk][ty*8+4];
            *(float4*)&b0[0] = *(const float4*)&Bt[kk][tx*4];
            for (int i = 0; i < 8; i++)
                for (int j = 0; j < 4; j++)
                    acc[i][j] += a0[i] * b0[j];
        }
        __syncthreads();
    }
    for (int i = 0; i < 8; i++) {
        int r = row0 + ty*8 + i;
        for (int j = 0; j < 4; j++) {
            int c = col0 + tx*4 + j;
            if (c < ncols) C[(size_t)r*ldc + c] = acc[i][j];
        }
    }
}

// ------------------------------------------------------------------
// fp64-accumulated indexer projection: Pd[8192][128] = x @ Wi_cat
// ------------------------------------------------------------------
__global__ __launch_bounds__(256) void k_proj64(const float* __restrict__ A,
                                                const float* __restrict__ W,
                                                double* __restrict__ P) {
    __shared__ float At[16][32];
    __shared__ float Bt[16][IDX_COLS];
    const int t  = threadIdx.x;
    const int tx = t & 15;
    const int ty = t >> 4;
    const int row0 = blockIdx.x * 32;
    double acc[2][8] = {};

    for (int k0 = 0; k0 < DMODEL; k0 += 16) {
        if (t < 128) {
            int m = t >> 2, kc = t & 3;
            float4 a = *(const float4*)(A + (size_t)(row0 + m)*DMODEL + k0 + kc*4);
            At[kc*4+0][m] = a.x; At[kc*4+1][m] = a.y;
            At[kc*4+2][m] = a.z; At[kc*4+3][m] = a.w;
        }
        for (int i = 0; i < 2; i++) {
            int lin = t + i*256;
            int kk = lin >> 5, c4 = lin & 31;
            float4 b = *(const float4*)(W + (size_t)(k0+kk)*IDX_COLS + c4*4);
            *(float4*)&Bt[kk][c4*4] = b;
        }
        __syncthreads();
        for (int kk = 0; kk < 16; kk++) {
            float a2[2], b8[8];
            a2[0] = At[kk][ty*2]; a2[1] = At[kk][ty*2+1];
            *(float4*)&b8[0] = *(const float4*)&Bt[kk][tx*8];
            *(float4*)&b8[4] = *(const float4*)&Bt[kk][tx*8+4];
            for (int i = 0; i < 2; i++)
                for (int j = 0; j < 8; j++)
                    acc[i][j] += (double)a2[i] * (double)b8[j];
        }
        __syncthreads();
    }
    for (int i = 0; i < 2; i++)
        for (int j = 0; j < 8; j++)
            P[(size_t)(row0 + ty*2 + i)*IDX_COLS + tx*8 + j] = acc[i][j];
}

// ------------------------------------------------------------------
// fp64 index scores
// ------------------------------------------------------------------
__global__ __launch_bounds__(256) void k_score64(const double* __restrict__ P,
                                                 double* __restrict__ S, int qstart) {
    __shared__ double qi0t[32][32];
    __shared__ double qi1t[32][32];
    __shared__ double kit[32][128];
    __shared__ double wsh[2][32];
    const int t = threadIdx.x;
    const int g0 = qstart + blockIdx.y * 32;
    const int b  = g0 / NSEQ;
    const int s0 = blockIdx.x * 128;

    for (int i = 0; i < 8; i++) {
        int lin = t + i*256;
        int q = lin >> 6, c = lin & 63;
        double v = P[(size_t)(g0 + q)*IDX_COLS + P_QI + c];
        if (c < 32) qi0t[c][q] = v; else qi1t[c-32][q] = v;
    }
    for (int i = 0; i < 16; i++) {
        int lin = t + i*256;
        int s = lin >> 5, c = lin & 31;
        kit[c][s] = P[(size_t)(b*NSEQ + s0 + s)*IDX_COLS + P_KI + c];
    }
    if (t < 64) wsh[t & 1][t >> 1] = P[(size_t)(g0 + (t >> 1))*IDX_COLS + P_W + (t & 1)];
    __syncthreads();

    const int tx = t & 15;
    const int ty = t >> 4;
    double acc0[2][8] = {}, acc1[2][8] = {};
    for (int d = 0; d < 32; d++) {
        double b8[8], a0[2], a1[2];
        for (int j = 0; j < 8; j++) b8[j] = kit[d][tx*8 + j];
        a0[0] = qi0t[d][ty*2]; a0[1] = qi0t[d][ty*2+1];
        a1[0] = qi1t[d][ty*2]; a1[1] = qi1t[d][ty*2+1];
        for (int i = 0; i < 2; i++)
            for (int j = 0; j < 8; j++) {
                acc0[i][j] += a0[i] * b8[j];
                acc1[i][j] += a1[i] * b8[j];
            }
    }
    for (int i = 0; i < 2; i++) {
        int q = ty*2 + i;
        double w0 = wsh[0][q], w1 = wsh[1][q];
        for (int j = 0; j < 8; j++) {
            double sc = w0 * fmax(acc0[i][j], 0.0) + w1 * fmax(acc1[i][j], 0.0);
            S[(size_t)(blockIdx.y*32 + q)*NSEQ + s0 + tx*8 + j] = sc;
        }
    }
}

// ------------------------------------------------------------------
// Fast top-128: hi32 radix select w/ early exit; lo32 only on hi-ties.
// Output SET semantics (order-free); ties at threshold -> lowest index.
// One block (256 thr) per query. LDS ~19KB.
// ------------------------------------------------------------------
__global__ __launch_bounds__(256) void k_topk(const double* __restrict__ S,
                                              int* __restrict__ IDX, int qstart) {
    __shared__ unsigned int key[NSEQ + NSEQ/16];   // padded: 17408 B
    __shared__ unsigned int candMask[NSEQ/32];     // 512 B
    __shared__ unsigned int hist[256];             // 1 KB
    __shared__ unsigned int s_ph, s_need, s_flag, s_cnt;
    __shared__ unsigned int wsum[4];
    const int t = threadIdx.x;
    const int lane = t & 63;
    const int wid = t >> 6;
    const int q = blockIdx.x;
    const double* row = S + (size_t)q * NSEQ;
    int* orow = IDX + (size_t)(qstart + q) * TOPK;

    auto pad = [](int i) { return i + (i >> 4); };

    // decision on current histogram: wave0 suffix-scans 256 bins via shfl
    auto decide = [&]() {
        if (wid == 0) {
            unsigned int c0 = hist[lane*4+0], c1 = hist[lane*4+1],
                         c2 = hist[lane*4+2], c3 = hist[lane*4+3];
            unsigned int s0l = c0 + c1 + c2 + c3;
            unsigned int run = s0l;
            for (int d = 1; d < 64; d <<= 1) {
                unsigned int v = __shfl_down(run, d, 64);
                if (lane + d < 64) run += v;
            }
            // run = count of elements with digit >= 4*lane (among candidates)
            unsigned int need = s_need;
            unsigned int Sb[5];
            Sb[0] = run;
            Sb[1] = run - c0;
            Sb[2] = Sb[1] - c1;
            Sb[3] = Sb[2] - c2;
            Sb[4] = Sb[3] - c3;
            for (int j = 0; j < 4; j++) {
                if (Sb[j] >= need && Sb[j+1] < need) {
                    unsigned int digit   = (unsigned int)(lane*4 + j);
                    unsigned int newneed = need - Sb[j+1];
                    unsigned int binCnt  = Sb[j] - Sb[j+1];
                    s_ph   = (s_ph << 8) | digit;
                    s_need = newneed;
                    if (newneed == binCnt) s_flag = 1;   // take whole bin
                }
            }
        }
        __syncthreads();
    };

    // ---- init + coalesced load (hi32 keys) + fused pass-0 histogram ----
    hist[t] = 0;
    if (t == 0) { s_ph = 0; s_need = TOPK; s_flag = 0; s_cnt = 0; }
    __syncthreads();
    for (int j = 0; j < 16; j++) {
        int i = t + 256*j;
        unsigned long long b = (unsigned long long)__double_as_longlong(row[i]);
        unsigned long long u = (b & 0x8000000000000000ULL) ? ~b : (b | 0x8000000000000000ULL);
        unsigned int h = (unsigned int)(u >> 32);
        key[pad(i)] = h;
        atomicAdd(&hist[h >> 24], 1u);
    }
    __syncthreads();

    // ---- stage A: radix select on hi32 ----
    decide();
    int plen = 8;
    for (int p = 1; p < 4; p++) {
        if (s_flag) break;
        const int sh = 24 - 8*p;
        hist[t] = 0;
        __syncthreads();
        unsigned int ph = s_ph;
        for (int j = 0; j < 16; j++) {
            int i = t*16 + j;
            unsigned int h = key[pad(i)];
            if ((h >> (sh+8)) == ph) atomicAdd(&hist[(h >> sh) & 255u], 1u);
        }
        __syncthreads();
        decide();
        plen += 8;
    }

    if (s_flag) {
        // take all with top-plen bits >= prefix (count == 128 exactly)
        unsigned int P = s_ph;
        int shr = 32 - plen;
        for (int j = 0; j < 16; j++) {
            int i = t*16 + j;
            unsigned int h = key[pad(i)];
            if ((h >> shr) >= P) {
                unsigned int pos = atomicAdd(&s_cnt, 1u);
                orow[pos] = i;
            }
        }
        return;
    }

    // ---- stage B: hi fully resolved, ties remain. n' = s_need of E cands ----
    unsigned int Hstar = s_ph;
    if (t < 128) candMask[t] = 0;
    __syncthreads();
    if (t == 0) s_ph = 0;
    // strict-hi collect + candidate mask + rewrite key[] with lo32
    for (int j = 0; j < 16; j++) {
        int i = t + 256*j;
        unsigned int h = key[pad(i)];
        if (h > Hstar) {
            unsigned int pos = atomicAdd(&s_cnt, 1u);
            orow[pos] = i;
        } else if (h == Hstar) {
            atomicOr(&candMask[i >> 5], 1u << (i & 31));
            unsigned long long b = (unsigned long long)__double_as_longlong(row[i]);
            unsigned long long u = (b & 0x8000000000000000ULL) ? ~b : (b | 0x8000000000000000ULL);
            key[pad(i)] = (unsigned int)u;   // lo32
        }
    }
    __syncthreads();

    int plenB = 0;
    for (int p = 0; p < 4; p++) {
        if (s_flag) break;
        const int sh = 24 - 8*p;
        hist[t] = 0;
        __syncthreads();
        unsigned int ph = s_ph;
        for (int j = 0; j < 16; j++) {
            int i = t*16 + j;
            if (candMask[i >> 5] & (1u << (i & 31))) {
                unsigned int h = key[pad(i)];
                if (p == 0 || (h >> (sh+8)) == ph) atomicAdd(&hist[(h >> sh) & 255u], 1u);
            }
        }
        __syncthreads();
        decide();
        plenB += 8;
    }

    if (s_flag) {
        unsigned int P = s_ph;
        int shr = 32 - plenB;
        for (int j = 0; j < 16; j++) {
            int i = t*16 + j;
            if (candMask[i >> 5] & (1u << (i & 31))) {
                unsigned int h = key[pad(i)];
                if ((h >> shr) >= P) {
                    unsigned int pos = atomicAdd(&s_cnt, 1u);
                    orow[pos] = i;
                }
            }
        }
        return;
    }

    // ---- full 64-bit resolved with exact ties: take lowest-index r ties ----
    unsigned int Lstar = s_ph;
    unsigned int r = s_need;
    unsigned int cnt = 0;
    for (int j = 0; j < 16; j++) {
        int i = t*16 + j;
        if (candMask[i >> 5] & (1u << (i & 31))) {
            unsigned int h = key[pad(i)];
            if (h > Lstar) {
                unsigned int pos = atomicAdd(&s_cnt, 1u);
                orow[pos] = i;
            } else if (h == Lstar) cnt++;
        }
    }
    // exclusive scan of tie counts over 256 threads (ascending index order)
    unsigned int inc = cnt;
    for (int d = 1; d < 64; d <<= 1) {
        unsigned int v = __shfl_up(inc, d, 64);
        if (lane >= d) inc += v;
    }
    if (lane == 63) wsum[wid] = inc;
    __syncthreads();
    unsigned int woff = 0;
    for (int w2 = 0; w2 < wid; w2++) woff += wsum[w2];
    unsigned int rk = woff + inc - cnt;       // exclusive prefix = tie rank base
    unsigned int tbase = TOPK - r;
    for (int j = 0; j < 16; j++) {
        int i = t*16 + j;
        if (candMask[i >> 5] & (1u << (i & 31))) {
            unsigned int h = key[pad(i)];
            if (h == Lstar) {
                if (rk < r) orow[tbase + rk] = i;
                rk++;
            }
        }
    }
}

// ------------------------------------------------------------------
// Sparse attention: per query, 8 heads over 128 selected keys (fp32)
// ------------------------------------------------------------------
__global__ __launch_bounds__(256) void k_attn(const float* __restrict__ Y,
                                              const int* __restrict__ IDX,
                                              float* __restrict__ ctx) {
    __shared__ float Ks[TOPK][DKQ];
    __shared__ float Vs[TOPK][DV];
    __shared__ float qsh[NH*DKQ];
    __shared__ float probs[NH][TOPK];
    __shared__ int   idxs[TOPK];
    const int g = blockIdx.x;
    const int b = g / NSEQ;
    const int t = threadIdx.x;

    if (t < TOPK) idxs[t] = IDX[(size_t)g*TOPK + t];
    for (int i = t; i < NH*DKQ; i += 256) qsh[i] = Y[(size_t)g*QKV_COLS + C_Q + i];
    __syncthreads();
    for (int e = t; e < TOPK*DKQ; e += 256) {
        int j = e / DKQ, dd = e % DKQ;
        size_t roff = (size_t)(b*NSEQ + idxs[j]) * QKV_COLS;
        Ks[j][dd] = Y[roff + C_K + dd];
        Vs[j][dd] = Y[roff + C_V + dd];
    }
    __syncthreads();

    const int h  = t >> 5;
    const int j0 = t & 31;
    float lo[4];
    for (int i = 0; i < 4; i++) {
        int j = j0 + 32*i;
        float acc = 0.f;
        for (int dd = 0; dd < DKQ; dd++) acc += qsh[h*DKQ + dd] * Ks[j][dd];
        lo[i] = acc * ATT_SCALE;
    }
    float m = fmaxf(fmaxf(lo[0], lo[1]), fmaxf(lo[2], lo[3]));
    for (int d = 16; d >= 1; d >>= 1) m = fmaxf(m, __shfl_xor(m, d, 64));
    float e0[4], sum = 0.f;
    for (int i = 0; i < 4; i++) { e0[i] = __expf(lo[i] - m); sum += e0[i]; }
    for (int d = 16; d >= 1; d >>= 1) sum += __shfl_xor(sum, d, 64);
    float inv = 1.0f / sum;
    for (int i = 0; i < 4; i++) probs[h][j0 + 32*i] = e0[i] * inv;
    __syncthreads();

    for (int o = t; o < NH*DV; o += 256) {
        int hh = o / DV, dd = o % DV;
        float acc = 0.f;
        for (int j = 0; j < TOPK; j++) acc += probs[hh][j] * Vs[j][dd];
        ctx[(size_t)g*(NH*DV) + o] = acc;
    }
}

// ------------------------------------------------------------------
extern "C" void kernel_launch(void* const* d_in, const int* in_sizes, int n_in,
                              void* d_out, int out_size, void* d_ws, size_t ws_size,
                              hipStream_t stream) {
    const float* x      = (const float*)d_in[0];
    const float* wq_idx = (const float*)d_in[1];
    const float* wk_idx = (const float*)d_in[2];
    const float* ww_idx = (const float*)d_in[3];
    const float* wq     = (const float*)d_in[4];
    const float* wk     = (const float*)d_in[5];
    const float* wv     = (const float*)d_in[6];
    const float* wo     = (const float*)d_in[7];
    float* out = (float*)d_out;
    char*  ws  = (char*)d_ws;

    size_t off = 0;
    auto carve = [&](size_t bytes) { size_t o = off; off = (off + bytes + 255) & ~(size_t)255; return o; };
    size_t oWq  = carve((size_t)DMODEL*QKV_COLS*4);
    size_t oWi  = carve((size_t)DMODEL*IDX_COLS*4);
    size_t oY   = carve((size_t)NQ*QKV_COLS*4);
    size_t oP   = carve((size_t)NQ*IDX_COLS*8);
    size_t oIdx = carve((size_t)NQ*TOPK*4);
    size_t oCtx = carve((size_t)NQ*NH*DV*4);
    size_t oS   = off;

    int QC = NSEQ;
    while (QC > 32 && oS + (size_t)QC*NSEQ*8 > ws_size) QC >>= 1;

    float*  Wq_cat = (float*)(ws + oWq);
    float*  Wi_cat = (float*)(ws + oWi);
    float*  Y      = (float*)(ws + oY);
    double* P      = (double*)(ws + oP);
    int*    IDX    = (int*)(ws + oIdx);
    float*  ctx    = (float*)(ws + oCtx);
    double* S      = (double*)(ws + oS);

    int ncat = DMODEL*QKV_COLS + DMODEL*IDX_COLS;
    k_concat<<<(ncat + 255)/256, 256, 0, stream>>>(wq_idx, wk_idx, ww_idx, wq, wk, wv, Wq_cat, Wi_cat);
    k_gemm384<<<dim3((QKV_COLS + 63)/64, NQ/128), 256, 0, stream>>>(x, Wq_cat, Y, QKV_COLS, QKV_COLS, QKV_COLS);
    k_proj64<<<NQ/32, 256, 0, stream>>>(x, Wi_cat, P);
    for (int qs = 0; qs < NQ; qs += QC) {
        k_score64<<<dim3(NSEQ/128, QC/32), 256, 0, stream>>>(P, S, qs);
        k_topk<<<QC, 256, 0, stream>>>(S, IDX, qs);
    }
    k_attn<<<NQ, 256, 0, stream>>>(Y, IDX, ctx);
    k_gemm384<<<dim3(DMODEL/64, NQ/128), 256, 0, stream>>>(ctx, wo, out, DMODEL, DMODEL, DMODEL);
}

// Round 5
// 669.889 us; speedup vs baseline: 1.6822x; 1.2445x over previous
//
#include <hip/hip_runtime.h>
#include <math.h>

// ---- problem dims ----
#define NB 2
#define NSEQ 4096
#define DMODEL 384
#define NH 8
#define DKQ 48
#define DV 48
#define TOPK 128
#define NQ (NB*NSEQ)          // 8192 total query rows

// fp32 combined projection: [q(384) | k(48) | v(48)] = 480 cols
#define QKV_COLS 480
#define C_Q 0
#define C_K 384
#define C_V 432
// fp64 indexer projection Pd[8192][128]: [qi0(32)|qi1(32)|ki(32)|w(2)|pad]
#define IDX_COLS 128
#define P_QI 0
#define P_KI 64
#define P_W  96
#define ATT_SCALE 0.14433756729740643f   // 48^-0.5

typedef double v4d __attribute__((ext_vector_type(4)));

// ------------------------------------------------------------------
// Kernel 0: concatenate weights
// ------------------------------------------------------------------
__global__ void k_concat(const float* __restrict__ wq_idx, const float* __restrict__ wk_idx,
                         const float* __restrict__ ww_idx, const float* __restrict__ wq,
                         const float* __restrict__ wk, const float* __restrict__ wv,
                         float* __restrict__ Wq_cat, float* __restrict__ Wi_cat) {
    int i = blockIdx.x * 256 + threadIdx.x;
    if (i < DMODEL * QKV_COLS) {
        int d = i / QKV_COLS, c = i % QKV_COLS;
        float v;
        if (c < 384)      v = wq[d*384 + c];
        else if (c < 432) v = wk[d*48 + (c-384)];
        else              v = wv[d*48 + (c-432)];
        Wq_cat[i] = v;
    } else {
        int j = i - DMODEL * QKV_COLS;
        if (j < DMODEL * IDX_COLS) {
            int d = j / IDX_COLS, c = j % IDX_COLS;
            float v;
            if (c < 64)       v = wq_idx[d*64 + c];
            else if (c < 96)  v = wk_idx[d*32 + (c-64)];
            else if (c < 98)  v = ww_idx[d*2 + (c-96)];
            else              v = 0.f;
            Wi_cat[j] = v;
        }
    }
}

// ------------------------------------------------------------------
// fp32 GEMM: C[M x ncols] = A[M x 384] @ W[384 x ncols]
// ------------------------------------------------------------------
__global__ __launch_bounds__(256) void k_gemm384(const float* __restrict__ A,
                                                 const float* __restrict__ W,
                                                 float* __restrict__ C,
                                                 int ldw, int ldc, int ncols) {
    __shared__ float At[16][128];
    __shared__ float Bt[16][64];
    const int t  = threadIdx.x;
    const int tx = t & 15;
    const int ty = t >> 4;
    const int row0 = blockIdx.y * 128;
    const int col0 = blockIdx.x * 64;
    float acc[8][4] = {};

    for (int k0 = 0; k0 < DMODEL; k0 += 16) {
        for (int i = 0; i < 2; i++) {
            int lin = t + i*256;
            int m = lin >> 2, kc = lin & 3;
            float4 a = *(const float4*)(A + (size_t)(row0 + m)*DMODEL + k0 + kc*4);
            At[kc*4+0][m] = a.x; At[kc*4+1][m] = a.y;
            At[kc*4+2][m] = a.z; At[kc*4+3][m] = a.w;
        }
        {
            int kk = t >> 4, nc4 = t & 15;
            int col = col0 + nc4*4;
            float4 b;
            if (col + 3 < ncols) {
                b = *(const float4*)(W + (size_t)(k0+kk)*ldw + col);
            } else {
                float tmp[4];
                for (int j = 0; j < 4; j++)
                    tmp[j] = (col + j < ncols) ? W[(size_t)(k0+kk)*ldw + col + j] : 0.f;
                b = make_float4(tmp[0], tmp[1], tmp[2], tmp[3]);
            }
            *(float4*)&Bt[kk][nc4*4] = b;
        }
        __syncthreads();
        for (int kk = 0; kk < 16; kk++) {
            float a0[8], b0[4];
            *(float4*)&a0[0] = *(const float4*)&At[kk][ty*8];
            *(float4*)&a0[4] = *(const float4*)&At[kk][ty*8+4];
            *(float4*)&b0[0] = *(const float4*)&Bt[kk][tx*4];
            for (int i = 0; i < 8; i++)
                for (int j = 0; j < 4; j++)
                    acc[i][j] += a0[i] * b0[j];
        }
        __syncthreads();
    }
    for (int i = 0; i < 8; i++) {
        int r = row0 + ty*8 + i;
        for (int j = 0; j < 4; j++) {
            int c = col0 + tx*4 + j;
            if (c < ncols) C[(size_t)r*ldc + c] = acc[i][j];
        }
    }
}

// ------------------------------------------------------------------
// fp64-accumulated indexer projection: Pd[8192][128] = x @ Wi_cat
// ------------------------------------------------------------------
__global__ __launch_bounds__(256) void k_proj64(const float* __restrict__ A,
                                                const float* __restrict__ W,
                                                double* __restrict__ P) {
    __shared__ float At[16][32];
    __shared__ float Bt[16][IDX_COLS];
    const int t  = threadIdx.x;
    const int tx = t & 15;
    const int ty = t >> 4;
    const int row0 = blockIdx.x * 32;
    double acc[2][8] = {};

    for (int k0 = 0; k0 < DMODEL; k0 += 16) {
        if (t < 128) {
            int m = t >> 2, kc = t & 3;
            float4 a = *(const float4*)(A + (size_t)(row0 + m)*DMODEL + k0 + kc*4);
            At[kc*4+0][m] = a.x; At[kc*4+1][m] = a.y;
            At[kc*4+2][m] = a.z; At[kc*4+3][m] = a.w;
        }
        for (int i = 0; i < 2; i++) {
            int lin = t + i*256;
            int kk = lin >> 5, c4 = lin & 31;
            float4 b = *(const float4*)(W + (size_t)(k0+kk)*IDX_COLS + c4*4);
            *(float4*)&Bt[kk][c4*4] = b;
        }
        __syncthreads();
        for (int kk = 0; kk < 16; kk++) {
            float a2[2], b8[8];
            a2[0] = At[kk][ty*2]; a2[1] = At[kk][ty*2+1];
            *(float4*)&b8[0] = *(const float4*)&Bt[kk][tx*8];
            *(float4*)&b8[4] = *(const float4*)&Bt[kk][tx*8+4];
            for (int i = 0; i < 2; i++)
                for (int j = 0; j < 8; j++)
                    acc[i][j] += (double)a2[i] * (double)b8[j];
        }
        __syncthreads();
    }
    for (int i = 0; i < 2; i++)
        for (int j = 0; j < 8; j++)
            P[(size_t)(row0 + ty*2 + i)*IDX_COLS + tx*8 + j] = acc[i][j];
}

// ------------------------------------------------------------------
// fp64 index scores via MFMA f64 16x16x4 with SELF-CALIBRATED C/D
// layout: two probe MFMAs measure the lane/reg -> (row,col) map, so
// the epilogue is correct for any hardware fragment layout.
// Block: 32q x 128s, 4 waves (2x2), each wave 16q x 64s, 2 heads.
// ------------------------------------------------------------------
__global__ __launch_bounds__(256) void k_score_mfma(const double* __restrict__ P,
                                                    double* __restrict__ S, int qstart) {
    __shared__ double A0[32][33];    // [k][q] qi0  (pad -> 2-way max)
    __shared__ double A1[32][33];    // [k][q] qi1
    __shared__ double Bk[32][129];   // [k][s] ki
    __shared__ double wsh[2][32];
    const int t = threadIdx.x;
    const int lane = t & 63;
    const int wid = t >> 6;
    const int g0 = qstart + blockIdx.y * 32;
    const int b  = g0 / NSEQ;
    const int s0 = blockIdx.x * 128;

    // qi tiles: 32 rows x 64 cols, coalesced rows
    for (int i = 0; i < 8; i++) {
        int lin = t + i*256;            // 2048
        int q = lin >> 6, c = lin & 63;
        double v = P[(size_t)(g0 + q)*IDX_COLS + P_QI + c];
        if (c < 32) A0[c][q] = v; else A1[c-32][q] = v;
    }
    // ki tile: 128 rows x 32 cols
    for (int i = 0; i < 16; i++) {
        int lin = t + i*256;            // 4096
        int s = lin >> 5, c = lin & 31;
        Bk[c][s] = P[(size_t)(b*NSEQ + s0 + s)*IDX_COLS + P_KI + c];
    }
    if (t < 64) wsh[t & 1][t >> 1] = P[(size_t)(g0 + (t >> 1))*IDX_COLS + P_W + (t & 1)];

    const int qw = (wid & 1) * 16;
    const int sw = (wid >> 1) * 64;
    const int ml = lane & 15;           // my supply convention: m/n index
    const int kl = lane >> 4;           // my supply convention: k index

    // ---- layout calibration (robust to any lane->(idx,k) bijection) ----
    // probe1: A[m][k]=m+1 (all k), B=1  => D[m][n] = 4*(m+1)
    // probe2: A=1, B[k][n]=n+1 (all k)  => D[m][n] = 4*(n+1)
    v4d zero = (v4d){0.0, 0.0, 0.0, 0.0};
    v4d rowp = __builtin_amdgcn_mfma_f64_16x16x4f64((double)(ml+1), 1.0, zero, 0, 0, 0);
    v4d colp = __builtin_amdgcn_mfma_f64_16x16x4f64(1.0, (double)(ml+1), zero, 0, 0, 0);
    int rowm[4], colm[4];
    #pragma unroll
    for (int r = 0; r < 4; r++) {
        rowm[r] = (((int)(rowp[r] * 0.25 + 0.5)) - 1) & 15;
        colm[r] = (((int)(colp[r] * 0.25 + 0.5)) - 1) & 15;
    }

    __syncthreads();

    v4d acc0[4], acc1[4];
    #pragma unroll
    for (int st = 0; st < 4; st++) {
        acc0[st] = (v4d){0.0, 0.0, 0.0, 0.0};
        acc1[st] = (v4d){0.0, 0.0, 0.0, 0.0};
    }

    #pragma unroll
    for (int k4 = 0; k4 < 8; k4++) {
        int k = k4*4 + kl;
        double a0 = A0[k][qw + ml];
        double a1 = A1[k][qw + ml];
        #pragma unroll
        for (int st = 0; st < 4; st++) {
            double bb = Bk[k][sw + st*16 + ml];
            acc0[st] = __builtin_amdgcn_mfma_f64_16x16x4f64(a0, bb, acc0[st], 0, 0, 0);
            acc1[st] = __builtin_amdgcn_mfma_f64_16x16x4f64(a1, bb, acc1[st], 0, 0, 0);
        }
    }

    // epilogue via calibrated mapping
    #pragma unroll
    for (int reg = 0; reg < 4; reg++) {
        int q = qw + rowm[reg];
        double w0 = wsh[0][q], w1 = wsh[1][q];
        #pragma unroll
        for (int st = 0; st < 4; st++) {
            double sc = w0 * fmax(acc0[st][reg], 0.0) + w1 * fmax(acc1[st][reg], 0.0);
            S[(size_t)(blockIdx.y*32 + q)*NSEQ + s0 + sw + st*16 + colm[reg]] = sc;
        }
    }
}

// ------------------------------------------------------------------
// Fast top-128: hi32 radix select w/ early exit; lo32 only on hi-ties.
// ------------------------------------------------------------------
__global__ __launch_bounds__(256) void k_topk(const double* __restrict__ S,
                                              int* __restrict__ IDX, int qstart) {
    __shared__ unsigned int key[NSEQ + NSEQ/16];
    __shared__ unsigned int candMask[NSEQ/32];
    __shared__ unsigned int hist[256];
    __shared__ unsigned int s_ph, s_need, s_flag, s_cnt;
    __shared__ unsigned int wsum[4];
    const int t = threadIdx.x;
    const int lane = t & 63;
    const int wid = t >> 6;
    const int q = blockIdx.x;
    const double* row = S + (size_t)q * NSEQ;
    int* orow = IDX + (size_t)(qstart + q) * TOPK;

    auto pad = [](int i) { return i + (i >> 4); };

    auto decide = [&]() {
        if (wid == 0) {
            unsigned int c0 = hist[lane*4+0], c1 = hist[lane*4+1],
                         c2 = hist[lane*4+2], c3 = hist[lane*4+3];
            unsigned int run = c0 + c1 + c2 + c3;
            for (int d = 1; d < 64; d <<= 1) {
                unsigned int v = __shfl_down(run, d, 64);
                if (lane + d < 64) run += v;
            }
            unsigned int need = s_need;
            unsigned int Sb[5];
            Sb[0] = run;
            Sb[1] = run - c0;
            Sb[2] = Sb[1] - c1;
            Sb[3] = Sb[2] - c2;
            Sb[4] = Sb[3] - c3;
            for (int j = 0; j < 4; j++) {
                if (Sb[j] >= need && Sb[j+1] < need) {
                    unsigned int digit   = (unsigned int)(lane*4 + j);
                    unsigned int newneed = need - Sb[j+1];
                    unsigned int binCnt  = Sb[j] - Sb[j+1];
                    s_ph   = (s_ph << 8) | digit;
                    s_need = newneed;
                    if (newneed == binCnt) s_flag = 1;
                }
            }
        }
        __syncthreads();
    };

    hist[t] = 0;
    if (t == 0) { s_ph = 0; s_need = TOPK; s_flag = 0; s_cnt = 0; }
    __syncthreads();
    for (int j = 0; j < 16; j++) {
        int i = t + 256*j;
        unsigned long long bb = (unsigned long long)__double_as_longlong(row[i]);
        unsigned long long u = (bb & 0x8000000000000000ULL) ? ~bb : (bb | 0x8000000000000000ULL);
        unsigned int h = (unsigned int)(u >> 32);
        key[pad(i)] = h;
        atomicAdd(&hist[h >> 24], 1u);
    }
    __syncthreads();

    decide();
    int plen = 8;
    for (int p = 1; p < 4; p++) {
        if (s_flag) break;
        const int sh = 24 - 8*p;
        hist[t] = 0;
        __syncthreads();
        unsigned int ph = s_ph;
        for (int j = 0; j < 16; j++) {
            int i = t*16 + j;
            unsigned int h = key[pad(i)];
            if ((h >> (sh+8)) == ph) atomicAdd(&hist[(h >> sh) & 255u], 1u);
        }
        __syncthreads();
        decide();
        plen += 8;
    }

    if (s_flag) {
        unsigned int P = s_ph;
        int shr = 32 - plen;
        for (int j = 0; j < 16; j++) {
            int i = t*16 + j;
            unsigned int h = key[pad(i)];
            if ((h >> shr) >= P) {
                unsigned int pos = atomicAdd(&s_cnt, 1u);
                orow[pos] = i;
            }
        }
        return;
    }

    unsigned int Hstar = s_ph;
    if (t < 128) candMask[t] = 0;
    __syncthreads();
    if (t == 0) s_ph = 0;
    for (int j = 0; j < 16; j++) {
        int i = t + 256*j;
        unsigned int h = key[pad(i)];
        if (h > Hstar) {
            unsigned int pos = atomicAdd(&s_cnt, 1u);
            orow[pos] = i;
        } else if (h == Hstar) {
            atomicOr(&candMask[i >> 5], 1u << (i & 31));
            unsigned long long bb = (unsigned long long)__double_as_longlong(row[i]);
            unsigned long long u = (bb & 0x8000000000000000ULL) ? ~bb : (bb | 0x8000000000000000ULL);
            key[pad(i)] = (unsigned int)u;
        }
    }
    __syncthreads();

    int plenB = 0;
    for (int p = 0; p < 4; p++) {
        if (s_flag) break;
        const int sh = 24 - 8*p;
        hist[t] = 0;
        __syncthreads();
        unsigned int ph = s_ph;
        for (int j = 0; j < 16; j++) {
            int i = t*16 + j;
            if (candMask[i >> 5] & (1u << (i & 31))) {
                unsigned int h = key[pad(i)];
                if (p == 0 || (h >> (sh+8)) == ph) atomicAdd(&hist[(h >> sh) & 255u], 1u);
            }
        }
        __syncthreads();
        decide();
        plenB += 8;
    }

    if (s_flag) {
        unsigned int P = s_ph;
        int shr = 32 - plenB;
        for (int j = 0; j < 16; j++) {
            int i = t*16 + j;
            if (candMask[i >> 5] & (1u << (i & 31))) {
                unsigned int h = key[pad(i)];
                if ((h >> shr) >= P) {
                    unsigned int pos = atomicAdd(&s_cnt, 1u);
                    orow[pos] = i;
                }
            }
        }
        return;
    }

    unsigned int Lstar = s_ph;
    unsigned int r = s_need;
    unsigned int cnt = 0;
    for (int j = 0; j < 16; j++) {
        int i = t*16 + j;
        if (candMask[i >> 5] & (1u << (i & 31))) {
            unsigned int h = key[pad(i)];
            if (h > Lstar) {
                unsigned int pos = atomicAdd(&s_cnt, 1u);
                orow[pos] = i;
            } else if (h == Lstar) cnt++;
        }
    }
    unsigned int inc = cnt;
    for (int d = 1; d < 64; d <<= 1) {
        unsigned int v = __shfl_up(inc, d, 64);
        if (lane >= d) inc += v;
    }
    if (lane == 63) wsum[wid] = inc;
    __syncthreads();
    unsigned int woff = 0;
    for (int w2 = 0; w2 < wid; w2++) woff += wsum[w2];
    unsigned int rk = woff + inc - cnt;
    unsigned int tbase = TOPK - r;
    for (int j = 0; j < 16; j++) {
        int i = t*16 + j;
        if (candMask[i >> 5] & (1u << (i & 31))) {
            unsigned int h = key[pad(i)];
            if (h == Lstar) {
                if (rk < r) orow[tbase + rk] = i;
                rk++;
            }
        }
    }
}

// ------------------------------------------------------------------
// Sparse attention: per query, 8 heads over 128 selected keys (fp32).
// Ks/Vs padded to 50 (<=2-way banks).
// ------------------------------------------------------------------
#define KVP 50
__global__ __launch_bounds__(256) void k_attn(const float* __restrict__ Y,
                                              const int* __restrict__ IDX,
                                              float* __restrict__ ctx) {
    __shared__ float Ks[TOPK][KVP];
    __shared__ float Vs[TOPK][KVP];
    __shared__ float qsh[NH*DKQ];
    __shared__ float probs[NH][TOPK];
    const int g = blockIdx.x;
    const int b = g / NSEQ;
    const int t = threadIdx.x;

    for (int i = t; i < NH*DKQ; i += 256) qsh[i] = Y[(size_t)g*QKV_COLS + C_Q + i];
    {
        int j = t >> 1, half = t & 1;
        int idx = IDX[(size_t)g*TOPK + j];
        const float* src = Y + (size_t)(b*NSEQ + idx) * QKV_COLS;
        #pragma unroll
        for (int qd = 0; qd < 6; qd++) {
            int c = half*24 + qd*4;
            float4 kk = *(const float4*)(src + C_K + c);
            float4 vv = *(const float4*)(src + C_V + c);
            Ks[j][c+0] = kk.x; Ks[j][c+1] = kk.y; Ks[j][c+2] = kk.z; Ks[j][c+3] = kk.w;
            Vs[j][c+0] = vv.x; Vs[j][c+1] = vv.y; Vs[j][c+2] = vv.z; Vs[j][c+3] = vv.w;
        }
    }
    __syncthreads();

    const int h  = t >> 5;
    const int j0 = t & 31;
    float lo[4];
    #pragma unroll
    for (int i = 0; i < 4; i++) {
        int j = j0 + 32*i;
        float acc = 0.f;
        for (int dd = 0; dd < DKQ; dd++) acc += qsh[h*DKQ + dd] * Ks[j][dd];
        lo[i] = acc * ATT_SCALE;
    }
    float m = fmaxf(fmaxf(lo[0], lo[1]), fmaxf(lo[2], lo[3]));
    for (int d = 16; d >= 1; d >>= 1) m = fmaxf(m, __shfl_xor(m, d, 64));
    float e0[4], sum = 0.f;
    #pragma unroll
    for (int i = 0; i < 4; i++) { e0[i] = __expf(lo[i] - m); sum += e0[i]; }
    for (int d = 16; d >= 1; d >>= 1) sum += __shfl_xor(sum, d, 64);
    float inv = 1.0f / sum;
    #pragma unroll
    for (int i = 0; i < 4; i++) probs[h][j0 + 32*i] = e0[i] * inv;
    __syncthreads();

    for (int o = t; o < NH*DV; o += 256) {
        int hh = o / DV, dd = o % DV;
        float acc = 0.f;
        for (int j = 0; j < TOPK; j++) acc += probs[hh][j] * Vs[j][dd];
        ctx[(size_t)g*(NH*DV) + o] = acc;
    }
}

// ------------------------------------------------------------------
extern "C" void kernel_launch(void* const* d_in, const int* in_sizes, int n_in,
                              void* d_out, int out_size, void* d_ws, size_t ws_size,
                              hipStream_t stream) {
    const float* x      = (const float*)d_in[0];
    const float* wq_idx = (const float*)d_in[1];
    const float* wk_idx = (const float*)d_in[2];
    const float* ww_idx = (const float*)d_in[3];
    const float* wq     = (const float*)d_in[4];
    const float* wk     = (const float*)d_in[5];
    const float* wv     = (const float*)d_in[6];
    const float* wo     = (const float*)d_in[7];
    float* out = (float*)d_out;
    char*  ws  = (char*)d_ws;

    size_t off = 0;
    auto carve = [&](size_t bytes) { size_t o = off; off = (off + bytes + 255) & ~(size_t)255; return o; };
    size_t oWq  = carve((size_t)DMODEL*QKV_COLS*4);
    size_t oWi  = carve((size_t)DMODEL*IDX_COLS*4);
    size_t oY   = carve((size_t)NQ*QKV_COLS*4);
    size_t oP   = carve((size_t)NQ*IDX_COLS*8);
    size_t oIdx = carve((size_t)NQ*TOPK*4);
    size_t oCtx = carve((size_t)NQ*NH*DV*4);
    size_t oS   = off;

    int QC = NSEQ;
    while (QC > 32 && oS + (size_t)QC*NSEQ*8 > ws_size) QC >>= 1;

    float*  Wq_cat = (float*)(ws + oWq);
    float*  Wi_cat = (float*)(ws + oWi);
    float*  Y      = (float*)(ws + oY);
    double* P      = (double*)(ws + oP);
    int*    IDX    = (int*)(ws + oIdx);
    float*  ctx    = (float*)(ws + oCtx);
    double* S      = (double*)(ws + oS);

    int ncat = DMODEL*QKV_COLS + DMODEL*IDX_COLS;
    k_concat<<<(ncat + 255)/256, 256, 0, stream>>>(wq_idx, wk_idx, ww_idx, wq, wk, wv, Wq_cat, Wi_cat);
    k_gemm384<<<dim3((QKV_COLS + 63)/64, NQ/128), 256, 0, stream>>>(x, Wq_cat, Y, QKV_COLS, QKV_COLS, QKV_COLS);
    k_proj64<<<NQ/32, 256, 0, stream>>>(x, Wi_cat, P);
    for (int qs = 0; qs < NQ; qs += QC) {
        k_score_mfma<<<dim3(NSEQ/128, QC/32), 256, 0, stream>>>(P, S, qs);
        k_topk<<<QC, 256, 0, stream>>>(S, IDX, qs);
    }
    k_attn<<<NQ, 256, 0, stream>>>(Y, IDX, ctx);
    k_gemm384<<<dim3(DMODEL/64, NQ/128), 256, 0, stream>>>(ctx, wo, out, DMODEL, DMODEL, DMODEL);
}

// Round 7
// 586.747 us; speedup vs baseline: 1.9205x; 1.1417x over previous
//
#include <hip/hip_runtime.h>
#include <math.h>

// ---- problem dims ----
#define NB 2
#define NSEQ 4096
#define DMODEL 384
#define NH 8
#define DKQ 48
#define DV 48
#define TOPK 128
#define NQ (NB*NSEQ)          // 8192 total query rows

// fp32 combined projection: [q(384) | k(48) | v(48)] = 480 cols
#define QKV_COLS 480
#define C_Q 0
#define C_K 384
#define C_V 432
// fp64 indexer projection Pd[8192][128]: [qi0(32)|qi1(32)|ki(32)|w(2)|pad]
#define IDX_COLS 128
#define P_QI 0
#define P_KI 64
#define P_W  96
#define ATT_SCALE 0.14433756729740643f   // 48^-0.5

typedef double v4d  __attribute__((ext_vector_type(4)));
typedef float  f32x4 __attribute__((ext_vector_type(4)));
typedef short  s16x8 __attribute__((ext_vector_type(8)));

// round-to-nearest-even bf16 split: v ~= hi + lo
__device__ inline void bsplit(float v, unsigned short& h, unsigned short& l) {
    unsigned hb = __float_as_uint(v);
    unsigned short hi = (unsigned short)((hb + 0x7FFFu + ((hb >> 16) & 1u)) >> 16);
    float hf = __uint_as_float(((unsigned)hi) << 16);
    float r = v - hf;
    unsigned rb = __float_as_uint(r);
    unsigned short lo = (unsigned short)((rb + 0x7FFFu + ((rb >> 16) & 1u)) >> 16);
    h = hi; l = lo;
}

// ------------------------------------------------------------------
// split x into bf16 hi/lo
// ------------------------------------------------------------------
__global__ void k_split(const float* __restrict__ x,
                        unsigned short* __restrict__ xhi, unsigned short* __restrict__ xlo) {
    int i = blockIdx.x * 256 + threadIdx.x;
    if (i < NQ * DMODEL) {
        unsigned short h, l;
        bsplit(x[i], h, l);
        xhi[i] = h; xlo[i] = l;
    }
}

// ------------------------------------------------------------------
// concat + transpose + split weights:
//  WqT[480][384] (bf16 hi/lo)  from [wq|wk|wv]
//  WoT[384][384] (bf16 hi/lo)  = wo^T
//  Wi_cat[384][128] fp32       = [wq_idx|wk_idx|ww_idx|pad]
// ------------------------------------------------------------------
__global__ void k_concat(const float* __restrict__ wq_idx, const float* __restrict__ wk_idx,
                         const float* __restrict__ ww_idx, const float* __restrict__ wq,
                         const float* __restrict__ wk, const float* __restrict__ wv,
                         const float* __restrict__ wo,
                         unsigned short* __restrict__ WqT_hi, unsigned short* __restrict__ WqT_lo,
                         unsigned short* __restrict__ WoT_hi, unsigned short* __restrict__ WoT_lo,
                         float* __restrict__ Wi_cat) {
    int i = blockIdx.x * 256 + threadIdx.x;
    const int NQK = QKV_COLS * DMODEL;          // 184320
    const int NWO = DMODEL * DMODEL;            // 147456
    if (i < NQK) {
        int n = i / DMODEL, k = i % DMODEL;
        float v;
        if (n < 384)      v = wq[(size_t)k*384 + n];
        else if (n < 432) v = wk[(size_t)k*48 + (n-384)];
        else              v = wv[(size_t)k*48 + (n-432)];
        unsigned short h, l; bsplit(v, h, l);
        WqT_hi[i] = h; WqT_lo[i] = l;
    } else if (i < NQK + NWO) {
        int j = i - NQK;
        int n = j / DMODEL, k = j % DMODEL;
        float v = wo[(size_t)k*384 + n];
        unsigned short h, l; bsplit(v, h, l);
        WoT_hi[j] = h; WoT_lo[j] = l;
    } else if (i < NQK + NWO + DMODEL*IDX_COLS) {
        int j = i - NQK - NWO;
        int d = j / IDX_COLS, c = j % IDX_COLS;
        float v;
        if (c < 64)       v = wq_idx[d*64 + c];
        else if (c < 96)  v = wk_idx[d*32 + (c-64)];
        else if (c < 98)  v = ww_idx[d*2 + (c-96)];
        else              v = 0.f;
        Wi_cat[j] = v;
    }
}

// ------------------------------------------------------------------
// split-bf16 MFMA GEMM: C[M x N] = (Ahi+Alo)[M x 384] @ (Bhi+Blo)^T
// A row-major [M][384] bf16; B stored transposed [N][384] bf16.
// 3-term split product. Block 128m x 64n, 4 waves 2x2, BK=32.
// Self-calibrated C/D layout.
// ------------------------------------------------------------------
#define GLDK 40   // shorts per LDS row (32 + 8 pad)
__global__ __launch_bounds__(256) void k_gemm_mfma(
        const unsigned short* __restrict__ Ahi, const unsigned short* __restrict__ Alo,
        const unsigned short* __restrict__ Bhi, const unsigned short* __restrict__ Blo,
        float* __restrict__ C, int N, int ldc) {
    __shared__ unsigned short At[2][128][GLDK];
    __shared__ unsigned short Bt[2][64][GLDK];
    const int t = threadIdx.x;
    const int lane = t & 63, wid = t >> 6;
    const int row0 = blockIdx.y * 128, col0 = blockIdx.x * 64;
    const int ml = lane & 15, kq = lane >> 4;
    const int wm = (wid & 1) * 64, wn = (wid >> 1) * 32;

    // ---- layout calibration probes ----
    unsigned short mv = (unsigned short)(__float_as_uint((float)(ml + 1)) >> 16);
    unsigned short one = 0x3F80;
    s16x8 pa, pb;
    #pragma unroll
    for (int j = 0; j < 8; j++) { pa[j] = (short)mv; pb[j] = (short)one; }
    f32x4 zf = (f32x4){0.f, 0.f, 0.f, 0.f};
    f32x4 rowp = __builtin_amdgcn_mfma_f32_16x16x32_bf16(pa, pb, zf, 0, 0, 0);
    f32x4 colp = __builtin_amdgcn_mfma_f32_16x16x32_bf16(pb, pa, zf, 0, 0, 0);
    int rowm[4], colm[4];
    #pragma unroll
    for (int r = 0; r < 4; r++) {
        rowm[r] = (((int)(rowp[r] * 0.03125f + 0.5f)) - 1) & 15;
        colm[r] = (((int)(colp[r] * 0.03125f + 0.5f)) - 1) & 15;
    }

    f32x4 acc[4][2];
    #pragma unroll
    for (int mt = 0; mt < 4; mt++)
        #pragma unroll
        for (int nt = 0; nt < 2; nt++) acc[mt][nt] = zf;

    for (int k0 = 0; k0 < DMODEL; k0 += 32) {
        // stage A: 1024 16B-chunks (2 arrays x 128 rows x 4 pieces)
        #pragma unroll
        for (int i = 0; i < 4; i++) {
            int ch = t + 256*i;
            int arr = ch >> 9, rem = ch & 511;
            int r = rem >> 2, p = rem & 3;
            const unsigned short* src = arr ? Alo : Ahi;
            *(int4*)&At[arr][r][p*8] = *(const int4*)(src + (size_t)(row0 + r)*DMODEL + k0 + p*8);
        }
        // stage B: 512 chunks (2 arrays x 64 rows x 4 pieces), N-guarded
        #pragma unroll
        for (int i = 0; i < 2; i++) {
            int ch = t + 256*i;
            int arr = ch >> 8, rem = ch & 255;
            int r = rem >> 2, p = rem & 3;
            const unsigned short* src = arr ? Blo : Bhi;
            int gc = col0 + r;
            int4 v = {0, 0, 0, 0};
            if (gc < N) v = *(const int4*)(src + (size_t)gc*DMODEL + k0 + p*8);
            *(int4*)&Bt[arr][r][p*8] = v;
        }
        __syncthreads();
        s16x8 af[4][2], bfr[2][2];
        #pragma unroll
        for (int mt = 0; mt < 4; mt++)
            #pragma unroll
            for (int h = 0; h < 2; h++)
                af[mt][h] = *(const s16x8*)&At[h][wm + mt*16 + ml][kq*8];
        #pragma unroll
        for (int nt = 0; nt < 2; nt++)
            #pragma unroll
            for (int h = 0; h < 2; h++)
                bfr[nt][h] = *(const s16x8*)&Bt[h][wn + nt*16 + ml][kq*8];
        #pragma unroll
        for (int mt = 0; mt < 4; mt++)
            #pragma unroll
            for (int nt = 0; nt < 2; nt++) {
                acc[mt][nt] = __builtin_amdgcn_mfma_f32_16x16x32_bf16(af[mt][0], bfr[nt][0], acc[mt][nt], 0, 0, 0);
                acc[mt][nt] = __builtin_amdgcn_mfma_f32_16x16x32_bf16(af[mt][0], bfr[nt][1], acc[mt][nt], 0, 0, 0);
                acc[mt][nt] = __builtin_amdgcn_mfma_f32_16x16x32_bf16(af[mt][1], bfr[nt][0], acc[mt][nt], 0, 0, 0);
            }
        __syncthreads();
    }
    #pragma unroll
    for (int mt = 0; mt < 4; mt++)
        #pragma unroll
        for (int nt = 0; nt < 2; nt++)
            #pragma unroll
            for (int r = 0; r < 4; r++) {
                int rr = row0 + wm + mt*16 + rowm[r];
                int cc = col0 + wn + nt*16 + colm[r];
                if (cc < N) C[(size_t)rr*ldc + cc] = acc[mt][nt][r];
            }
}

// ------------------------------------------------------------------
// fp64-accumulated indexer projection: Pd[8192][128] = x @ Wi_cat
// ------------------------------------------------------------------
__global__ __launch_bounds__(256) void k_proj64(const float* __restrict__ A,
                                                const float* __restrict__ W,
                                                double* __restrict__ P) {
    __shared__ float At[16][32];
    __shared__ float Bt[16][IDX_COLS];
    const int t  = threadIdx.x;
    const int tx = t & 15;
    const int ty = t >> 4;
    const int row0 = blockIdx.x * 32;
    double acc[2][8] = {};

    for (int k0 = 0; k0 < DMODEL; k0 += 16) {
        if (t < 128) {
            int m = t >> 2, kc = t & 3;
            float4 a = *(const float4*)(A + (size_t)(row0 + m)*DMODEL + k0 + kc*4);
            At[kc*4+0][m] = a.x; At[kc*4+1][m] = a.y;
            At[kc*4+2][m] = a.z; At[kc*4+3][m] = a.w;
        }
        for (int i = 0; i < 2; i++) {
            int lin = t + i*256;
            int kk = lin >> 5, c4 = lin & 31;
            float4 b = *(const float4*)(W + (size_t)(k0+kk)*IDX_COLS + c4*4);
            *(float4*)&Bt[kk][c4*4] = b;
        }
        __syncthreads();
        for (int kk = 0; kk < 16; kk++) {
            float a2[2], b8[8];
            a2[0] = At[kk][ty*2]; a2[1] = At[kk][ty*2+1];
            *(float4*)&b8[0] = *(const float4*)&Bt[kk][tx*8];
            *(float4*)&b8[4] = *(const float4*)&Bt[kk][tx*8+4];
            for (int i = 0; i < 2; i++)
                for (int j = 0; j < 8; j++)
                    acc[i][j] += (double)a2[i] * (double)b8[j];
        }
        __syncthreads();
    }
    for (int i = 0; i < 2; i++)
        for (int j = 0; j < 8; j++)
            P[(size_t)(row0 + ty*2 + i)*IDX_COLS + tx*8 + j] = acc[i][j];
}

// ------------------------------------------------------------------
// fp64 index scores via MFMA f64 16x16x4, self-calibrated C/D layout.
// ------------------------------------------------------------------
__global__ __launch_bounds__(256) void k_score_mfma(const double* __restrict__ P,
                                                    double* __restrict__ S, int qstart) {
    __shared__ double A0[32][33];
    __shared__ double A1[32][33];
    __shared__ double Bk[32][129];
    __shared__ double wsh[2][32];
    const int t = threadIdx.x;
    const int lane = t & 63;
    const int wid = t >> 6;
    const int g0 = qstart + blockIdx.y * 32;
    const int b  = g0 / NSEQ;
    const int s0 = blockIdx.x * 128;

    for (int i = 0; i < 8; i++) {
        int lin = t + i*256;
        int q = lin >> 6, c = lin & 63;
        double v = P[(size_t)(g0 + q)*IDX_COLS + P_QI + c];
        if (c < 32) A0[c][q] = v; else A1[c-32][q] = v;
    }
    for (int i = 0; i < 16; i++) {
        int lin = t + i*256;
        int s = lin >> 5, c = lin & 31;
        Bk[c][s] = P[(size_t)(b*NSEQ + s0 + s)*IDX_COLS + P_KI + c];
    }
    if (t < 64) wsh[t & 1][t >> 1] = P[(size_t)(g0 + (t >> 1))*IDX_COLS + P_W + (t & 1)];

    const int qw = (wid & 1) * 16;
    const int sw = (wid >> 1) * 64;
    const int ml = lane & 15;
    const int kl = lane >> 4;

    v4d zero = (v4d){0.0, 0.0, 0.0, 0.0};
    v4d rowp = __builtin_amdgcn_mfma_f64_16x16x4f64((double)(ml+1), 1.0, zero, 0, 0, 0);
    v4d colp = __builtin_amdgcn_mfma_f64_16x16x4f64(1.0, (double)(ml+1), zero, 0, 0, 0);
    int rowm[4], colm[4];
    #pragma unroll
    for (int r = 0; r < 4; r++) {
        rowm[r] = (((int)(rowp[r] * 0.25 + 0.5)) - 1) & 15;
        colm[r] = (((int)(colp[r] * 0.25 + 0.5)) - 1) & 15;
    }

    __syncthreads();

    v4d acc0[4], acc1[4];
    #pragma unroll
    for (int st = 0; st < 4; st++) { acc0[st] = zero; acc1[st] = zero; }

    #pragma unroll
    for (int k4 = 0; k4 < 8; k4++) {
        int k = k4*4 + kl;
        double a0 = A0[k][qw + ml];
        double a1 = A1[k][qw + ml];
        #pragma unroll
        for (int st = 0; st < 4; st++) {
            double bb = Bk[k][sw + st*16 + ml];
            acc0[st] = __builtin_amdgcn_mfma_f64_16x16x4f64(a0, bb, acc0[st], 0, 0, 0);
            acc1[st] = __builtin_amdgcn_mfma_f64_16x16x4f64(a1, bb, acc1[st], 0, 0, 0);
        }
    }

    #pragma unroll
    for (int reg = 0; reg < 4; reg++) {
        int q = qw + rowm[reg];
        double w0 = wsh[0][q], w1 = wsh[1][q];
        #pragma unroll
        for (int st = 0; st < 4; st++) {
            double sc = w0 * fmax(acc0[st][reg], 0.0) + w1 * fmax(acc1[st][reg], 0.0);
            S[(size_t)(blockIdx.y*32 + q)*NSEQ + s0 + sw + st*16 + colm[reg]] = sc;
        }
    }
}

// ------------------------------------------------------------------
// Fast top-128: hi32 radix select w/ early exit; lo32 only on hi-ties.
// ------------------------------------------------------------------
__global__ __launch_bounds__(256) void k_topk(const double* __restrict__ S,
                                              int* __restrict__ IDX, int qstart) {
    __shared__ unsigned int key[NSEQ + NSEQ/16];
    __shared__ unsigned int candMask[NSEQ/32];
    __shared__ unsigned int hist[256];
    __shared__ unsigned int s_ph, s_need, s_flag, s_cnt;
    __shared__ unsigned int wsum[4];
    const int t = threadIdx.x;
    const int lane = t & 63;
    const int wid = t >> 6;
    const int q = blockIdx.x;
    const double* row = S + (size_t)q * NSEQ;
    int* orow = IDX + (size_t)(qstart + q) * TOPK;

    auto pad = [](int i) { return i + (i >> 4); };

    auto decide = [&]() {
        if (wid == 0) {
            unsigned int c0 = hist[lane*4+0], c1 = hist[lane*4+1],
                         c2 = hist[lane*4+2], c3 = hist[lane*4+3];
            unsigned int run = c0 + c1 + c2 + c3;
            for (int d = 1; d < 64; d <<= 1) {
                unsigned int v = __shfl_down(run, d, 64);
                if (lane + d < 64) run += v;
            }
            unsigned int need = s_need;
            unsigned int Sb[5];
            Sb[0] = run;
            Sb[1] = run - c0;
            Sb[2] = Sb[1] - c1;
            Sb[3] = Sb[2] - c2;
            Sb[4] = Sb[3] - c3;
            for (int j = 0; j < 4; j++) {
                if (Sb[j] >= need && Sb[j+1] < need) {
                    unsigned int digit   = (unsigned int)(lane*4 + j);
                    unsigned int newneed = need - Sb[j+1];
                    unsigned int binCnt  = Sb[j] - Sb[j+1];
                    s_ph   = (s_ph << 8) | digit;
                    s_need = newneed;
                    if (newneed == binCnt) s_flag = 1;
                }
            }
        }
        __syncthreads();
    };

    hist[t] = 0;
    if (t == 0) { s_ph = 0; s_need = TOPK; s_flag = 0; s_cnt = 0; }
    __syncthreads();
    for (int j = 0; j < 16; j++) {
        int i = t + 256*j;
        unsigned long long bb = (unsigned long long)__double_as_longlong(row[i]);
        unsigned long long u = (bb & 0x8000000000000000ULL) ? ~bb : (bb | 0x8000000000000000ULL);
        unsigned int h = (unsigned int)(u >> 32);
        key[pad(i)] = h;
        atomicAdd(&hist[h >> 24], 1u);
    }
    __syncthreads();

    decide();
    int plen = 8;
    for (int p = 1; p < 4; p++) {
        if (s_flag) break;
        const int sh = 24 - 8*p;
        hist[t] = 0;
        __syncthreads();
        unsigned int ph = s_ph;
        for (int j = 0; j < 16; j++) {
            int i = t*16 + j;
            unsigned int h = key[pad(i)];
            if ((h >> (sh+8)) == ph) atomicAdd(&hist[(h >> sh) & 255u], 1u);
        }
        __syncthreads();
        decide();
        plen += 8;
    }

    if (s_flag) {
        unsigned int P = s_ph;
        int shr = 32 - plen;
        for (int j = 0; j < 16; j++) {
            int i = t*16 + j;
            unsigned int h = key[pad(i)];
            if ((h >> shr) >= P) {
                unsigned int pos = atomicAdd(&s_cnt, 1u);
                orow[pos] = i;
            }
        }
        return;
    }

    unsigned int Hstar = s_ph;
    if (t < 128) candMask[t] = 0;
    __syncthreads();
    if (t == 0) s_ph = 0;
    for (int j = 0; j < 16; j++) {
        int i = t + 256*j;
        unsigned int h = key[pad(i)];
        if (h > Hstar) {
            unsigned int pos = atomicAdd(&s_cnt, 1u);
            orow[pos] = i;
        } else if (h == Hstar) {
            atomicOr(&candMask[i >> 5], 1u << (i & 31));
            unsigned long long bb = (unsigned long long)__double_as_longlong(row[i]);
            unsigned long long u = (bb & 0x8000000000000000ULL) ? ~bb : (bb | 0x8000000000000000ULL);
            key[pad(i)] = (unsigned int)u;
        }
    }
    __syncthreads();

    int plenB = 0;
    for (int p = 0; p < 4; p++) {
        if (s_flag) break;
        const int sh = 24 - 8*p;
        hist[t] = 0;
        __syncthreads();
        unsigned int ph = s_ph;
        for (int j = 0; j < 16; j++) {
            int i = t*16 + j;
            if (candMask[i >> 5] & (1u << (i & 31))) {
                unsigned int h = key[pad(i)];
                if (p == 0 || (h >> (sh+8)) == ph) atomicAdd(&hist[(h >> sh) & 255u], 1u);
            }
        }
        __syncthreads();
        decide();
        plenB += 8;
    }

    if (s_flag) {
        unsigned int P = s_ph;
        int shr = 32 - plenB;
        for (int j = 0; j < 16; j++) {
            int i = t*16 + j;
            if (candMask[i >> 5] & (1u << (i & 31))) {
                unsigned int h = key[pad(i)];
                if ((h >> shr) >= P) {
                    unsigned int pos = atomicAdd(&s_cnt, 1u);
                    orow[pos] = i;
                }
            }
        }
        return;
    }

    unsigned int Lstar = s_ph;
    unsigned int r = s_need;
    unsigned int cnt = 0;
    for (int j = 0; j < 16; j++) {
        int i = t*16 + j;
        if (candMask[i >> 5] & (1u << (i & 31))) {
            unsigned int h = key[pad(i)];
            if (h > Lstar) {
                unsigned int pos = atomicAdd(&s_cnt, 1u);
                orow[pos] = i;
            } else if (h == Lstar) cnt++;
        }
    }
    unsigned int inc = cnt;
    for (int d = 1; d < 64; d <<= 1) {
        unsigned int v = __shfl_up(inc, d, 64);
        if (lane >= d) inc += v;
    }
    if (lane == 63) wsum[wid] = inc;
    __syncthreads();
    unsigned int woff = 0;
    for (int w2 = 0; w2 < wid; w2++) woff += wsum[w2];
    unsigned int rk = woff + inc - cnt;
    unsigned int tbase = TOPK - r;
    for (int j = 0; j < 16; j++) {
        int i = t*16 + j;
        if (candMask[i >> 5] & (1u << (i & 31))) {
            unsigned int h = key[pad(i)];
            if (h == Lstar) {
                if (rk < r) orow[tbase + rk] = i;
                rk++;
            }
        }
    }
}

// ------------------------------------------------------------------
// Attention stage 1: logits + softmax -> probs (global)
// One block per query; LDS ~28.7KB -> 5 blocks/CU.
// ------------------------------------------------------------------
#define KVP 52
__global__ __launch_bounds__(256) void k_attn_qk(const float* __restrict__ Y,
                                                 const int* __restrict__ IDX,
                                                 float* __restrict__ Pr) {
    __shared__ float Ks[TOPK][KVP];
    __shared__ float qsh[NH*DKQ];
    __shared__ int   idxs[TOPK];
    const int g = blockIdx.x;
    const int b = g / NSEQ;
    const int t = threadIdx.x;

    if (t < TOPK) idxs[t] = IDX[(size_t)g*TOPK + t];
    for (int i = t; i < NH*DKQ; i += 256) qsh[i] = Y[(size_t)g*QKV_COLS + C_Q + i];
    __syncthreads();
    // gather K: 1536 float4 chunks, consecutive lanes -> consecutive pieces
    #pragma unroll
    for (int i = 0; i < 6; i++) {
        int e = t + 256*i;
        int j = e / 12, p = e % 12;
        const float* src = Y + (size_t)(b*NSEQ + idxs[j])*QKV_COLS + C_K;
        *(float4*)&Ks[j][p*4] = *(const float4*)(src + p*4);
    }
    __syncthreads();

    const int h  = t >> 5;
    const int j0 = t & 31;
    float lo[4] = {0.f, 0.f, 0.f, 0.f};
    #pragma unroll
    for (int c = 0; c < 12; c++) {
        float4 qv = *(const float4*)&qsh[h*DKQ + c*4];
        #pragma unroll
        for (int i = 0; i < 4; i++) {
            float4 kv = *(const float4*)&Ks[j0 + 32*i][c*4];
            lo[i] += qv.x*kv.x + qv.y*kv.y + qv.z*kv.z + qv.w*kv.w;
        }
    }
    #pragma unroll
    for (int i = 0; i < 4; i++) lo[i] *= ATT_SCALE;
    float m = fmaxf(fmaxf(lo[0], lo[1]), fmaxf(lo[2], lo[3]));
    for (int d = 16; d >= 1; d >>= 1) m = fmaxf(m, __shfl_xor(m, d, 64));
    float e0[4], sum = 0.f;
    #pragma unroll
    for (int i = 0; i < 4; i++) { e0[i] = __expf(lo[i] - m); sum += e0[i]; }
    for (int d = 16; d >= 1; d >>= 1) sum += __shfl_xor(sum, d, 64);
    float inv = 1.0f / sum;
    #pragma unroll
    for (int i = 0; i < 4; i++)
        Pr[(size_t)g*(NH*TOPK) + h*TOPK + j0 + 32*i] = e0[i] * inv;
}

// ------------------------------------------------------------------
// Attention stage 2: PV -> ctx (bf16 hi/lo split for out-proj GEMM)
// LDS ~31KB -> 5 blocks/CU.
// ------------------------------------------------------------------
__global__ __launch_bounds__(256) void k_attn_pv(const float* __restrict__ Y,
                                                 const int* __restrict__ IDX,
                                                 const float* __restrict__ Pr,
                                                 unsigned short* __restrict__ ctx_hi,
                                                 unsigned short* __restrict__ ctx_lo) {
    __shared__ float Vs[TOPK][KVP];
    __shared__ float prs[NH*TOPK];
    __shared__ int   idxs[TOPK];
    const int g = blockIdx.x;
    const int b = g / NSEQ;
    const int t = threadIdx.x;

    if (t < TOPK) idxs[t] = IDX[(size_t)g*TOPK + t];
    *(float4*)&prs[t*4] = *(const float4*)(Pr + (size_t)g*(NH*TOPK) + t*4);
    __syncthreads();
    #pragma unroll
    for (int i = 0; i < 6; i++) {
        int e = t + 256*i;
        int j = e / 12, p = e % 12;
        const float* src = Y + (size_t)(b*NSEQ + idxs[j])*QKV_COLS + C_V;
        *(float4*)&Vs[j][p*4] = *(const float4*)(src + p*4);
    }
    __syncthreads();

    for (int o = t; o < NH*DV; o += 256) {
        int hh = o / DV, dd = o % DV;
        float acc = 0.f;
        #pragma unroll
        for (int jc = 0; jc < 32; jc++) {
            float4 pv = *(const float4*)&prs[hh*TOPK + jc*4];
            acc += pv.x*Vs[jc*4+0][dd] + pv.y*Vs[jc*4+1][dd]
                 + pv.z*Vs[jc*4+2][dd] + pv.w*Vs[jc*4+3][dd];
        }
        unsigned short h, l;
        bsplit(acc, h, l);
        ctx_hi[(size_t)g*(NH*DV) + o] = h;
        ctx_lo[(size_t)g*(NH*DV) + o] = l;
    }
}

// ------------------------------------------------------------------
extern "C" void kernel_launch(void* const* d_in, const int* in_sizes, int n_in,
                              void* d_out, int out_size, void* d_ws, size_t ws_size,
                              hipStream_t stream) {
    const float* x      = (const float*)d_in[0];
    const float* wq_idx = (const float*)d_in[1];
    const float* wk_idx = (const float*)d_in[2];
    const float* ww_idx = (const float*)d_in[3];
    const float* wq     = (const float*)d_in[4];
    const float* wk     = (const float*)d_in[5];
    const float* wv     = (const float*)d_in[6];
    const float* wo     = (const float*)d_in[7];
    float* out = (float*)d_out;
    char*  ws  = (char*)d_ws;

    size_t off = 0;
    auto carve = [&](size_t bytes) { size_t o = off; off = (off + bytes + 255) & ~(size_t)255; return o; };
    size_t oWqh = carve((size_t)QKV_COLS*DMODEL*2);
    size_t oWql = carve((size_t)QKV_COLS*DMODEL*2);
    size_t oWoh = carve((size_t)DMODEL*DMODEL*2);
    size_t oWol = carve((size_t)DMODEL*DMODEL*2);
    size_t oWi  = carve((size_t)DMODEL*IDX_COLS*4);
    size_t oXh  = carve((size_t)NQ*DMODEL*2);
    size_t oXl  = carve((size_t)NQ*DMODEL*2);
    size_t oY   = carve((size_t)NQ*QKV_COLS*4);
    size_t oP   = carve((size_t)NQ*IDX_COLS*8);
    size_t oIdx = carve((size_t)NQ*TOPK*4);
    size_t oPr  = carve((size_t)NQ*NH*TOPK*4);
    size_t oCh  = carve((size_t)NQ*NH*DV*2);
    size_t oCl  = carve((size_t)NQ*NH*DV*2);
    size_t oS   = off;

    int QC = NSEQ;
    while (QC > 32 && oS + (size_t)QC*NSEQ*8 > ws_size) QC >>= 1;

    unsigned short* WqT_hi = (unsigned short*)(ws + oWqh);
    unsigned short* WqT_lo = (unsigned short*)(ws + oWql);
    unsigned short* WoT_hi = (unsigned short*)(ws + oWoh);
    unsigned short* WoT_lo = (unsigned short*)(ws + oWol);
    float*  Wi_cat = (float*)(ws + oWi);
    unsigned short* xhi = (unsigned short*)(ws + oXh);
    unsigned short* xlo = (unsigned short*)(ws + oXl);
    float*  Y      = (float*)(ws + oY);
    double* P      = (double*)(ws + oP);
    int*    IDX    = (int*)(ws + oIdx);
    float*  Pr     = (float*)(ws + oPr);
    unsigned short* ctx_hi = (unsigned short*)(ws + oCh);
    unsigned short* ctx_lo = (unsigned short*)(ws + oCl);
    double* S      = (double*)(ws + oS);

    int ncat = QKV_COLS*DMODEL + DMODEL*DMODEL + DMODEL*IDX_COLS;
    k_split<<<(NQ*DMODEL + 255)/256, 256, 0, stream>>>(x, xhi, xlo);
    k_concat<<<(ncat + 255)/256, 256, 0, stream>>>(wq_idx, wk_idx, ww_idx, wq, wk, wv, wo,
                                                   WqT_hi, WqT_lo, WoT_hi, WoT_lo, Wi_cat);
    k_gemm_mfma<<<dim3((QKV_COLS + 63)/64, NQ/128), 256, 0, stream>>>(xhi, xlo, WqT_hi, WqT_lo, Y, QKV_COLS, QKV_COLS);
    k_proj64<<<NQ/32, 256, 0, stream>>>(x, Wi_cat, P);
    for (int qs = 0; qs < NQ; qs += QC) {
        k_score_mfma<<<dim3(NSEQ/128, QC/32), 256, 0, stream>>>(P, S, qs);
        k_topk<<<QC, 256, 0, stream>>>(S, IDX, qs);
    }
    k_attn_qk<<<NQ, 256, 0, stream>>>(Y, IDX, Pr);
    k_attn_pv<<<NQ, 256, 0, stream>>>(Y, IDX, Pr, ctx_hi, ctx_lo);
    k_gemm_mfma<<<dim3(DMODEL/64, NQ/128), 256, 0, stream>>>(ctx_hi, ctx_lo, WoT_hi, WoT_lo, out, DMODEL, DMODEL);
}